// Round 8
// baseline (165.371 us; speedup 1.0000x reference)
//
#include <hip/hip_runtime.h>

#define IN_F 4096
#define OUT_F 4096
#define MTOK 1024   // 2*512 tokens
#define RANK 16
#define GROUP 128

typedef short bf16x8 __attribute__((ext_vector_type(8)));
typedef float f32x4 __attribute__((ext_vector_type(4)));

__device__ __forceinline__ unsigned short f2bf(float f) {
  unsigned int u = __float_as_uint(f);
  u += 0x7fff + ((u >> 16) & 1);   // round-to-nearest-even
  return (unsigned short)(u >> 16);
}

// ---------------- kernel 1: W_q = fake_quant(w0 + lora_b @ lora_a) -> bf16 ----------------
#define QROWS 8
__global__ __launch_bounds__(256) void quant_w(const float* __restrict__ w0,
                                               const float* __restrict__ la,
                                               const float* __restrict__ lb,
                                               const float* __restrict__ qs,
                                               unsigned short* __restrict__ wq) {
  const int bid = blockIdx.x;        // 2048 blocks: (4096/QROWS) rowgroups x 4 colblocks
  const int cb  = bid & 3;
  const int rg  = bid >> 2;
  const int i   = cb * 1024 + (threadIdx.x << 2);
  const int o0  = rg * QROWS;

  float4 areg[RANK];
  #pragma unroll
  for (int r = 0; r < RANK; ++r)
    areg[r] = *reinterpret_cast<const float4*>(&la[r * IN_F + i]);

  #pragma unroll
  for (int ro = 0; ro < QROWS; ++ro) {
    const int o = o0 + ro;
    float4 w = *reinterpret_cast<const float4*>(&w0[(size_t)o * IN_F + i]);
    const float* lbr = &lb[o * RANK];
    #pragma unroll
    for (int r = 0; r < RANK; ++r) {
      const float b = lbr[r];
      w.x = fmaf(b, areg[r].x, w.x);
      w.y = fmaf(b, areg[r].y, w.y);
      w.z = fmaf(b, areg[r].z, w.z);
      w.w = fmaf(b, areg[r].w, w.w);
    }
    const float s  = qs[o * (IN_F / GROUP) + (i >> 7)];
    const float se = s + 1e-9f;
    ushort4 ov;
    ov.x = f2bf(rintf(fminf(fmaxf(w.x / se, -8.f), 7.f)) * s);
    ov.y = f2bf(rintf(fminf(fmaxf(w.y / se, -8.f), 7.f)) * s);
    ov.z = f2bf(rintf(fminf(fmaxf(w.z / se, -8.f), 7.f)) * s);
    ov.w = f2bf(rintf(fminf(fmaxf(w.w / se, -8.f), 7.f)) * s);
    *reinterpret_cast<ushort4*>(&wq[(size_t)o * IN_F + i]) = ov;
  }
}

// ---------------- kernel 2: x f32 -> bf16 ----------------
__global__ __launch_bounds__(256) void cvt_x(const float* __restrict__ x,
                                             unsigned short* __restrict__ xb) {
  const int i = (blockIdx.x * 256 + threadIdx.x) << 2;
  float4 v = *reinterpret_cast<const float4*>(&x[i]);
  ushort4 ov;
  ov.x = f2bf(v.x); ov.y = f2bf(v.y); ov.z = f2bf(v.z); ov.w = f2bf(v.w);
  *reinterpret_cast<ushort4*>(&xb[i]) = ov;
}

// ---------------- kernel 3: C[M,N] = A[M,K]*B[N,K]^T + bias, bf16 MFMA ----------------
// Block tile 128x64, 256 threads = 4 waves (2M x 2N), wave tile 64x32. No split-K.
// B (wq) staged in LDS, double-buffered, 16KB total (rows 128B, row&7 chunk-XOR,
// source-side swizzle, linear LDS dest). A (xb) read directly global->VGPR
// fragments; XCD swizzle (by = bid&7) pins one 128-row x-slice per XCD's L2.
// Staged volume: B only = (M/BM) * 33.5MB = 268MB. Direct C write (no reduce).
#define BM 128
#define BN 64
#define BK 64
#define NT (IN_F / BK)          // 64
#define BBUF (BN * BK)          // 4096 shorts = 8KB per buffer

__device__ __forceinline__ void load_lds16(const void* gsrc, void* ldst) {
  __builtin_amdgcn_global_load_lds(
      (const __attribute__((address_space(1))) unsigned int*)gsrc,
      (__attribute__((address_space(3))) unsigned int*)ldst, 16, 0, 0);
}

__global__ __launch_bounds__(256, 4) void gemm_bt(const unsigned short* __restrict__ A,
                                                  const unsigned short* __restrict__ B,
                                                  const float* __restrict__ bias,
                                                  float* __restrict__ C) {
  __shared__ unsigned short lds[2 * BBUF];   // 16KB
  const int tid  = threadIdx.x;
  const int lane = tid & 63;
  const int wave = tid >> 6;     // 0..3
  const int wr   = wave >> 1;    // M-half
  const int wc   = wave & 1;     // N-half
  const int r16  = lane & 15;
  const int hi   = lane >> 4;

  // grid 512 = 8 M-tiles x 64 N-tiles; XCD = bid%8 -> by, so each XCD's 64
  // blocks share one 128-row x-slice (L2-resident).
  const int bid = blockIdx.x;
  const int by  = bid & 7;
  const int bx  = bid >> 3;
  const int mBase = by * BM;
  const int nBase = bx * BN;

  // stage B tile: 64 rows x 128B = 512 chunks of 16B; 256 thr -> 2 each.
  // logical chunk-in-row = phys ^ (row&7); LDS dest linear.
  auto stage = [&](int buf, int kt) {
    const int kcol = kt * BK;
    #pragma unroll
    for (int j = 0; j < 2; ++j) {
      const int chunk = tid + j * 256;
      const int row   = chunk >> 3;               // 8 chunks per 64-short row
      const int clog  = (chunk & 7) ^ (row & 7);
      load_lds16(B + (size_t)(nBase + row) * IN_F + kcol + clog * 8,
                 &lds[buf * BBUF + chunk * 8]);
    }
  };

  f32x4 acc[4][2];
  #pragma unroll
  for (int m = 0; m < 4; ++m)
    #pragma unroll
    for (int n = 0; n < 2; ++n)
      acc[m][n] = (f32x4){0.f, 0.f, 0.f, 0.f};

  const unsigned short* Aw = A + (size_t)(mBase + wr * 64 + r16) * IN_F;

  stage(0, 0);
  int cur = 0;
  for (int kt = 0; kt < NT; ++kt) {
    __syncthreads();                     // stage(cur) complete; cur^1 free
    if (kt + 1 < NT) stage(cur ^ 1, kt + 1);

    // A fragments straight from global (L2-hot): 8 x 16B per lane
    bf16x8 af[2][4];
    #pragma unroll
    for (int kk = 0; kk < 2; ++kk)
      #pragma unroll
      for (int m = 0; m < 4; ++m)
        af[kk][m] = *reinterpret_cast<const bf16x8*>(
            Aw + (size_t)(m * 16) * IN_F + kt * BK + kk * 32 + hi * 8);

    const unsigned short* Ls = &lds[cur * BBUF];
    #pragma unroll
    for (int kk = 0; kk < 2; ++kk) {
      bf16x8 bq[2];
      #pragma unroll
      for (int n = 0; n < 2; ++n) {
        const int row = wc * 32 + n * 16 + r16;
        const int c   = (kk * 4 + hi) ^ (row & 7);
        bq[n] = *reinterpret_cast<const bf16x8*>(&Ls[row * BK + c * 8]);
      }
      #pragma unroll
      for (int m = 0; m < 4; ++m)
        #pragma unroll
        for (int n = 0; n < 2; ++n)
          acc[m][n] = __builtin_amdgcn_mfma_f32_16x16x32_bf16(af[kk][m], bq[n], acc[m][n], 0, 0, 0);
    }
    cur ^= 1;
  }

  // C/D layout: col = lane&15, row = hi*4 + j
  #pragma unroll
  for (int m = 0; m < 4; ++m) {
    const int rowg = mBase + wr * 64 + m * 16 + hi * 4;
    #pragma unroll
    for (int n = 0; n < 2; ++n) {
      const int colg = nBase + wc * 32 + n * 16 + r16;
      const float bv = bias[colg];
      #pragma unroll
      for (int j = 0; j < 4; ++j)
        C[(size_t)(rowg + j) * OUT_F + colg] = acc[m][n][j] + bv;
    }
  }
}

// ---------------- fallback (only if ws too small): direct recompute ----------------
__global__ void naive_out(const float* __restrict__ x, const float* __restrict__ w0,
                          const float* __restrict__ la, const float* __restrict__ lb,
                          const float* __restrict__ qs, const float* __restrict__ bias,
                          float* __restrict__ out) {
  const int n = blockIdx.x * 256 + threadIdx.x;
  const int m = blockIdx.y;
  const float* xr = &x[(size_t)m * IN_F];
  float acc = 0.f;
  for (int kg = 0; kg < IN_F / GROUP; ++kg) {
    const float s = qs[n * (IN_F / GROUP) + kg];
    const float se = s + 1e-9f;
    for (int k0 = 0; k0 < GROUP; ++k0) {
      const int k = kg * GROUP + k0;
      float w = w0[(size_t)n * IN_F + k];
      for (int r = 0; r < RANK; ++r) w = fmaf(lb[n * RANK + r], la[r * IN_F + k], w);
      const float q = rintf(fminf(fmaxf(w / se, -8.f), 7.f));
      acc = fmaf(xr[k], q * s, acc);
    }
  }
  out[(size_t)m * OUT_F + n] = acc + bias[n];
}

extern "C" void kernel_launch(void* const* d_in, const int* in_sizes, int n_in,
                              void* d_out, int out_size, void* d_ws, size_t ws_size,
                              hipStream_t stream) {
  const float* x    = (const float*)d_in[0];
  const float* w0   = (const float*)d_in[1];
  const float* la   = (const float*)d_in[2];
  const float* lb   = (const float*)d_in[3];
  const float* qs   = (const float*)d_in[4];
  const float* bias = (const float*)d_in[5];
  float* out = (float*)d_out;

  const size_t wq_bytes = (size_t)OUT_F * IN_F * 2;
  const size_t xb_bytes = (size_t)MTOK * IN_F * 2;

  if (ws_size >= wq_bytes + xb_bytes) {
    unsigned short* wq = (unsigned short*)d_ws;
    unsigned short* xb = (unsigned short*)((char*)d_ws + wq_bytes);
    quant_w<<<(OUT_F / QROWS) * 4, 256, 0, stream>>>(w0, la, lb, qs, wq);
    cvt_x<<<(MTOK * IN_F) / 1024, 256, 0, stream>>>(x, xb);
    // 512 blocks = 8 M x 64 N (bid%8 = M-tile = XCD)
    gemm_bt<<<(MTOK / BM) * (OUT_F / BN), 256, 0, stream>>>(xb, wq, bias, out);
  } else {
    dim3 grid(OUT_F / 256, MTOK);
    naive_out<<<grid, 256, 0, stream>>>(x, w0, la, lb, qs, bias, out);
  }
}

// Round 10
// 82.626 us; speedup vs baseline: 2.0014x; 2.0014x over previous
//
#include <hip/hip_runtime.h>

#define IN_F 4096
#define OUT_F 4096
#define MTOK 1024   // 2*512 tokens
#define RANK 16
#define GROUP 128

typedef short bf16x8 __attribute__((ext_vector_type(8)));
typedef float f32x4 __attribute__((ext_vector_type(4)));

__device__ __forceinline__ unsigned short f2bf(float f) {
  unsigned int u = __float_as_uint(f);
  u += 0x7fff + ((u >> 16) & 1);   // round-to-nearest-even
  return (unsigned short)(u >> 16);
}

// ---------------- kernel 1: W_q = fake_quant(w0 + lora_b @ lora_a) -> bf16 ----------------
#define QROWS 8
__global__ __launch_bounds__(256) void quant_w(const float* __restrict__ w0,
                                               const float* __restrict__ la,
                                               const float* __restrict__ lb,
                                               const float* __restrict__ qs,
                                               unsigned short* __restrict__ wq) {
  const int bid = blockIdx.x;        // 2048 blocks: (4096/QROWS) rowgroups x 4 colblocks
  const int cb  = bid & 3;
  const int rg  = bid >> 2;
  const int i   = cb * 1024 + (threadIdx.x << 2);
  const int o0  = rg * QROWS;

  float4 areg[RANK];
  #pragma unroll
  for (int r = 0; r < RANK; ++r)
    areg[r] = *reinterpret_cast<const float4*>(&la[r * IN_F + i]);

  #pragma unroll
  for (int ro = 0; ro < QROWS; ++ro) {
    const int o = o0 + ro;
    float4 w = *reinterpret_cast<const float4*>(&w0[(size_t)o * IN_F + i]);
    const float* lbr = &lb[o * RANK];
    #pragma unroll
    for (int r = 0; r < RANK; ++r) {
      const float b = lbr[r];
      w.x = fmaf(b, areg[r].x, w.x);
      w.y = fmaf(b, areg[r].y, w.y);
      w.z = fmaf(b, areg[r].z, w.z);
      w.w = fmaf(b, areg[r].w, w.w);
    }
    const float s  = qs[o * (IN_F / GROUP) + (i >> 7)];
    const float se = s + 1e-9f;
    ushort4 ov;
    ov.x = f2bf(rintf(fminf(fmaxf(w.x / se, -8.f), 7.f)) * s);
    ov.y = f2bf(rintf(fminf(fmaxf(w.y / se, -8.f), 7.f)) * s);
    ov.z = f2bf(rintf(fminf(fmaxf(w.z / se, -8.f), 7.f)) * s);
    ov.w = f2bf(rintf(fminf(fmaxf(w.w / se, -8.f), 7.f)) * s);
    *reinterpret_cast<ushort4*>(&wq[(size_t)o * IN_F + i]) = ov;
  }
}

// ---------------- kernel 2: x f32 -> bf16 ----------------
__global__ __launch_bounds__(256) void cvt_x(const float* __restrict__ x,
                                             unsigned short* __restrict__ xb) {
  const int i = (blockIdx.x * 256 + threadIdx.x) << 2;
  float4 v = *reinterpret_cast<const float4*>(&x[i]);
  ushort4 ov;
  ov.x = f2bf(v.x); ov.y = f2bf(v.y); ov.z = f2bf(v.z); ov.w = f2bf(v.w);
  *reinterpret_cast<ushort4*>(&xb[i]) = ov;
}

// ---------------- kernel 2b: C = bias (epilogue base for atomic K-split) ----------------
__global__ __launch_bounds__(256) void init_c(const float* __restrict__ bias,
                                              float* __restrict__ C) {
  const int i = blockIdx.x * 256 + threadIdx.x;       // float4 index
  const float4 b = *reinterpret_cast<const float4*>(&bias[(i & 1023) << 2]);
  *reinterpret_cast<float4*>(&C[(size_t)i << 2]) = b;
}

// ---------------- kernel 3: C += A[M,K]*B[N,K]^T (K split across blocks) ----------------
// Grid 512 = 2 K-halves x 8 M-tiles x 32 N-tiles; 128x128 tile, 256 thr = 4 waves
// (2x2), wave tile 64x64, BK=64. LDS 64KB (2 buf x (A128+B128)x64 shorts)
// -> 2 blocks/CU: two barrier domains cover each other's vmcnt drains (m114/m97).
// Rows 128B, row&7 chunk-XOR on the global source, linear LDS dest (R4: 0 conflicts).
// Each block atomicAdds its half-K partial onto C (pre-initialized with bias);
// exactly 2 commutative adds per element.
#define BM 128
#define BN 128
#define BK 64
#define KSPLIT 2
#define KHALF (IN_F / KSPLIT)   // 2048
#define NT (KHALF / BK)         // 32
#define TBUF ((BM + BN) * BK)   // 16384 shorts = 32KB per buffer

__device__ __forceinline__ void load_lds16(const void* gsrc, void* ldst) {
  __builtin_amdgcn_global_load_lds(
      (const __attribute__((address_space(1))) unsigned int*)gsrc,
      (__attribute__((address_space(3))) unsigned int*)ldst, 16, 0, 0);
}

__global__ __launch_bounds__(256, 2) void gemm_bt(const unsigned short* __restrict__ A,
                                                  const unsigned short* __restrict__ B,
                                                  float* __restrict__ C) {
  __shared__ unsigned short lds[2 * TBUF];   // 64KB
  const int tid  = threadIdx.x;
  const int lane = tid & 63;
  const int wave = tid >> 6;     // 0..3
  const int wr   = wave >> 1;    // M-half of tile
  const int wc   = wave & 1;     // N-half of tile
  const int r16  = lane & 15;
  const int hi   = lane >> 4;

  // bid = by*64 + bx*2 + kh: the 8 by-sharers of a B-panel differ by 64
  // (== 0 mod 8) -> same XCD; A-tile + B-panel stay L2/LLC-hot.
  const int bid = blockIdx.x;
  const int kh  = bid & 1;
  const int bx  = (bid >> 1) & 31;
  const int by  = bid >> 6;
  const int mBase = by * BM;
  const int nBase = bx * BN;
  const int kOff  = kh * KHALF;

  // stage both tiles: 256 rows x 8 chunks(16B) = 2048 chunks; 256 thr x 8 each.
  auto stage = [&](int buf, int kt) {
    const int kcol = kOff + kt * BK;
    #pragma unroll
    for (int j = 0; j < 8; ++j) {
      const int chunk = tid + j * 256;            // 0..2047
      const int row   = chunk >> 3;               // 0..255 (A: 0-127, B: 128-255)
      const int clog  = (chunk & 7) ^ (row & 7);
      const unsigned short* src = (row < BM)
          ? (A + (size_t)(mBase + row) * IN_F + kcol + clog * 8)
          : (B + (size_t)(nBase + row - BM) * IN_F + kcol + clog * 8);
      load_lds16(src, &lds[buf * TBUF + chunk * 8]);
    }
  };

  f32x4 acc[4][4];
  #pragma unroll
  for (int m = 0; m < 4; ++m)
    #pragma unroll
    for (int n = 0; n < 4; ++n)
      acc[m][n] = (f32x4){0.f, 0.f, 0.f, 0.f};

  stage(0, 0);
  int cur = 0;
  for (int kt = 0; kt < NT; ++kt) {
    __syncthreads();                     // stage(cur) complete; cur^1 free
    if (kt + 1 < NT) stage(cur ^ 1, kt + 1);
    const unsigned short* Ls = &lds[cur * TBUF];
    #pragma unroll
    for (int kk = 0; kk < 2; ++kk) {
      bf16x8 af[4], bq[4];
      #pragma unroll
      for (int m = 0; m < 4; ++m) {
        const int row = wr * 64 + m * 16 + r16;
        const int c   = (kk * 4 + hi) ^ (row & 7);
        af[m] = *reinterpret_cast<const bf16x8*>(&Ls[row * BK + c * 8]);
      }
      #pragma unroll
      for (int n = 0; n < 4; ++n) {
        const int row = wc * 64 + n * 16 + r16;
        const int c   = (kk * 4 + hi) ^ (row & 7);
        bq[n] = *reinterpret_cast<const bf16x8*>(&Ls[BM * BK + row * BK + c * 8]);
      }
      #pragma unroll
      for (int m = 0; m < 4; ++m)
        #pragma unroll
        for (int n = 0; n < 4; ++n)
          acc[m][n] = __builtin_amdgcn_mfma_f32_16x16x32_bf16(af[m], bq[n], acc[m][n], 0, 0, 0);
    }
    cur ^= 1;
  }

  // C/D layout: col = lane&15, row = hi*4 + j  [m89-verified]
  #pragma unroll
  for (int m = 0; m < 4; ++m) {
    const int rowg = mBase + wr * 64 + m * 16 + hi * 4;
    #pragma unroll
    for (int n = 0; n < 4; ++n) {
      const int colg = nBase + wc * 64 + n * 16 + r16;
      #pragma unroll
      for (int j = 0; j < 4; ++j)
        atomicAdd(&C[(size_t)(rowg + j) * OUT_F + colg], acc[m][n][j]);
    }
  }
}

// ---------------- fallback (only if ws too small): direct recompute ----------------
__global__ void naive_out(const float* __restrict__ x, const float* __restrict__ w0,
                          const float* __restrict__ la, const float* __restrict__ lb,
                          const float* __restrict__ qs, const float* __restrict__ bias,
                          float* __restrict__ out) {
  const int n = blockIdx.x * 256 + threadIdx.x;
  const int m = blockIdx.y;
  const float* xr = &x[(size_t)m * IN_F];
  float acc = 0.f;
  for (int kg = 0; kg < IN_F / GROUP; ++kg) {
    const float s = qs[n * (IN_F / GROUP) + kg];
    const float se = s + 1e-9f;
    for (int k0 = 0; k0 < GROUP; ++k0) {
      const int k = kg * GROUP + k0;
      float w = w0[(size_t)n * IN_F + k];
      for (int r = 0; r < RANK; ++r) w = fmaf(lb[n * RANK + r], la[r * IN_F + k], w);
      const float q = rintf(fminf(fmaxf(w / se, -8.f), 7.f));
      acc = fmaf(xr[k], q * s, acc);
    }
  }
  out[(size_t)m * OUT_F + n] = acc + bias[n];
}

extern "C" void kernel_launch(void* const* d_in, const int* in_sizes, int n_in,
                              void* d_out, int out_size, void* d_ws, size_t ws_size,
                              hipStream_t stream) {
  const float* x    = (const float*)d_in[0];
  const float* w0   = (const float*)d_in[1];
  const float* la   = (const float*)d_in[2];
  const float* lb   = (const float*)d_in[3];
  const float* qs   = (const float*)d_in[4];
  const float* bias = (const float*)d_in[5];
  float* out = (float*)d_out;

  const size_t wq_bytes = (size_t)OUT_F * IN_F * 2;
  const size_t xb_bytes = (size_t)MTOK * IN_F * 2;

  if (ws_size >= wq_bytes + xb_bytes) {
    unsigned short* wq = (unsigned short*)d_ws;
    unsigned short* xb = (unsigned short*)((char*)d_ws + wq_bytes);
    quant_w<<<(OUT_F / QROWS) * 4, 256, 0, stream>>>(w0, la, lb, qs, wq);
    cvt_x<<<(MTOK * IN_F) / 1024, 256, 0, stream>>>(x, xb);
    init_c<<<(MTOK * OUT_F) / 1024, 256, 0, stream>>>(bias, out);
    // 512 blocks = 2 K-halves x 8 M x 32 N; 2 blocks/CU
    gemm_bt<<<KSPLIT * (MTOK / BM) * (OUT_F / BN), 256, 0, stream>>>(xb, wq, out);
  } else {
    dim3 grid(OUT_F / 256, MTOK);
    naive_out<<<grid, 256, 0, stream>>>(x, w0, la, lb, qs, bias, out);
  }
}